// Round 4
// baseline (461.039 us; speedup 1.0000x reference)
//
#include <hip/hip_runtime.h>
#include <math.h>

#define C_DIM 256
#define N_DIM 19
#define HW 65536
#define CQ 64                          /* C_DIM/4 */
#define TBL (CQ * N_DIM * 8)           /* 9728 floats: interleaved {-P4, A4} */
#define PP_OFF TBL                     /* +n  */
#define PA_OFF (TBL + 32)              /* +n  */
#define AN_OFF (TBL + 64)              /* +n  */

// ---- prep: build interleaved table ws[(cq*19+n)*8] = {-P quad, normedA quad}
__global__ void prep_kernel(const float* __restrict__ P,
                            const float* __restrict__ A,
                            float* __restrict__ ws) {
    int n = blockIdx.x;          // one wave per n
    int lane = threadIdx.x;      // 64 lanes == 64 c-quads
    float4 pv = *reinterpret_cast<const float4*>(P + n * C_DIM + lane * 4);
    float4 av = *reinterpret_cast<const float4*>(A + n * C_DIM + lane * 4);
    float pp = pv.x * pv.x + pv.y * pv.y + pv.z * pv.z + pv.w * pv.w;
    float aa = av.x * av.x + av.y * av.y + av.z * av.z + av.w * av.w;
    float pa = pv.x * av.x + pv.y * av.y + pv.z * av.z + pv.w * av.w;
#pragma unroll
    for (int off = 32; off > 0; off >>= 1) {
        pp += __shfl_xor(pp, off);
        aa += __shfl_xor(aa, off);
        pa += __shfl_xor(pa, off);
    }
    float an  = sqrtf(aa);
    float inv = 1.0f / fmaxf(an, 1e-12f);

    float* o = ws + (size_t)(lane * N_DIM + n) * 8;
    o[0] = -pv.x; o[1] = -pv.y; o[2] = -pv.z; o[3] = -pv.w;
    o[4] = av.x * inv; o[5] = av.y * inv; o[6] = av.z * inv; o[7] = av.w * inv;

    if (lane == 0) {
        ws[PP_OFF + n] = pp;
        ws[PA_OFF + n] = -pa * inv;   // sum(-P * normed_A)
        ws[AN_OFF + n] = an;          // ||A_n||
    }
}

// ---- main: 1 pixel/thread; P/A read via wave-uniform global loads (L1-hot)
__global__ __launch_bounds__(256) void hyper_mlr_main(
    const float* __restrict__ x, const float* __restrict__ ws,
    float* __restrict__ out)
{
    int tid = blockIdx.x * 256 + threadIdx.x;
    int b   = tid >> 16;
    int hw  = tid & 65535;
    const float* xb = x + (size_t)b * C_DIM * HW + hw;

    float xx = 0.f;
    float px[N_DIM], xa[N_DIM];
#pragma unroll
    for (int n = 0; n < N_DIM; ++n) { px[n] = 0.f; xa[n] = 0.f; }

    float x0 = xb[0];
    float x1 = xb[(size_t)HW];
    float x2 = xb[(size_t)2 * HW];
    float x3 = xb[(size_t)3 * HW];

    for (int cq = 0; cq < CQ - 1; ++cq) {
        const float* xn = xb + (size_t)(cq + 1) * 4 * HW;
        float n0 = xn[0];
        float n1 = xn[(size_t)HW];
        float n2 = xn[(size_t)2 * HW];
        float n3 = xn[(size_t)3 * HW];

        xx += x0 * x0; xx += x1 * x1; xx += x2 * x2; xx += x3 * x3;
        const float* wq = ws + (size_t)cq * N_DIM * 8;   // wave-uniform base
#pragma unroll
        for (int n = 0; n < N_DIM; ++n) {
            float4 p = *reinterpret_cast<const float4*>(wq + n * 8);
            float4 a = *reinterpret_cast<const float4*>(wq + n * 8 + 4);
            px[n] += x0 * p.x; px[n] += x1 * p.y; px[n] += x2 * p.z; px[n] += x3 * p.w;
            xa[n] += x0 * a.x; xa[n] += x1 * a.y; xa[n] += x2 * a.z; xa[n] += x3 * a.w;
        }
        x0 = n0; x1 = n1; x2 = n2; x3 = n3;
    }
    {   // last c-quad
        const int cq = CQ - 1;
        xx += x0 * x0; xx += x1 * x1; xx += x2 * x2; xx += x3 * x3;
        const float* wq = ws + (size_t)cq * N_DIM * 8;
#pragma unroll
        for (int n = 0; n < N_DIM; ++n) {
            float4 p = *reinterpret_cast<const float4*>(wq + n * 8);
            float4 a = *reinterpret_cast<const float4*>(wq + n * 8 + 4);
            px[n] += x0 * p.x; px[n] += x1 * p.y; px[n] += x2 * p.z; px[n] += x3 * p.w;
            xa[n] += x0 * a.x; xa[n] += x1 * a.y; xa[n] += x2 * a.z; xa[n] += x3 * a.w;
        }
    }

    const float K        = 0.5f;
    const float sqK      = 0.70710678118654752f;          // sqrt(K)
    const float maxnorm  = 0.999f / sqK;                  // (1-PROJ_EPS)/sqrt(K)
    const float maxnorm2 = maxnorm * maxnorm;
    const float eps      = 1e-12f;

    float* ob = out + (size_t)b * N_DIM * HW + hw;
#pragma unroll
    for (int n = 0; n < N_DIM; ++n) {
        float pp = ws[PP_OFF + n];    // wave-uniform, L1-hot
        float pa = ws[PA_OFF + n];
        float an = ws[AN_OFF + n];
        float pxs = px[n], xas = xa[n];

        float Av = 1.0f + pxs + K * xx;                   // 2K = 1
        float Bv = 1.0f - K * pp;
        float D  = fmaxf(1.0f + pxs + (K * K) * xx * pp, eps);
        float alpha = Av / D, beta = Bv / D;
        float mob = alpha * alpha * pp + beta * beta * xx + 2.0f * alpha * beta * pxs;
        float sqrtm = sqrtf(fmaxf(mob, 0.0f));
        float proj = (sqrtm > maxnorm) ? (maxnorm / fmaxf(sqrtm, eps)) : 1.0f;
        float mobp = (sqrtm < maxnorm) ? mob : maxnorm2;
        float mobdota = (beta * xas + alpha * pa) * proj;
        float lamb = 2.0f / fmaxf(1.0f - K * mobp, eps);
        float sine = sqK * mobdota * lamb;
        ob[(size_t)n * HW] = (2.0f / sqK) * an * asinhf(sine);
    }
}

extern "C" void kernel_launch(void* const* d_in, const int* in_sizes, int n_in,
                              void* d_out, int out_size, void* d_ws, size_t ws_size,
                              hipStream_t stream) {
    const float* x  = (const float*)d_in[0];
    const float* P  = (const float*)d_in[1];
    const float* A  = (const float*)d_in[2];
    float* out = (float*)d_out;
    float* ws  = (float*)d_ws;

    prep_kernel<<<N_DIM, 64, 0, stream>>>(P, A, ws);
    hyper_mlr_main<<<1024, 256, 0, stream>>>(x, ws, out);
}